// Round 5
// baseline (17.927 us; speedup 1.0000x reference)
//
#include <hip/hip_runtime.h>
#include <cstdint>

// out[b,f,cout,r] = log( sum_cin exp(ll[b,f,cin,r]) * softmax_cin(logits)[f,cin,cout,r] )
// B=256, F=64, CIN=32, COUT=16, R=8
#define LOG2E 1.4426950408889634f
#define LN2   0.6931471805599453f

// One fused kernel. Grid = 1024 WGs (64 f x 16 b-tiles of 16), 256 threads (4 waves).
// => 4 WGs/CU co-resident (34.9 KB LDS each), 16 waves/CU.
// Wave w 0..3; lane l: r = w*2 + (l>>5), ch = (l>>4)&1 (cout half), b = l&15.
// LDS (floats):
//   Wb [0..4288)    softmax weights, 16 slices [r*2+ch] of stride 268: [cin][8 cout]
//   Eb [4288..8928) exp(ll): r-stride 580, b-stride 36, +cin   (then reused as out tile [16][132])
__global__ __launch_bounds__(256, 4) void fused_lse(const float* __restrict__ ll,
                                                    const float* __restrict__ logits,
                                                    float* __restrict__ out) {
    __shared__ float S[8928];
    float* Wb = S;
    float* Eb = S + 4288;
    float* T2 = S + 4288;                    // reuse of Eb region after barrier 2

    const int t = threadIdx.x;
    const int w = t >> 6;                    // wave 0..3
    const int l = t & 63;

    // XCD-bijective swizzle: XCD x gets f in [x*8, x*8+8), all 16 b-tiles per f.
    const int bid = (int)blockIdx.x;
    const int swz = ((bid & 7) << 7) + (bid >> 3);
    const int f   = swz >> 4;
    const int b0  = (swz & 15) << 4;

    // ---- A1: issue the cold ll loads FIRST (4 x float4 per thread) ----
    float4 v[4];
    const float* llb = ll + (((size_t)b0 * 64 + f) << 8) + l * 4;
    #pragma unroll
    for (int j = 0; j < 4; ++j) {
        const int row = j * 4 + w;           // 0..15, wave-uniform
        v[j] = *(const float4*)(llb + ((size_t)row << 14));   // row*64*256
    }

    // ---- A2: logits loads for softmax (threads 0..127; 256B/wave per c, L2-hot) ----
    float x[32];
    if (t < 128) {
        const float* lg = logits + ((size_t)f << 12) + t;
        #pragma unroll
        for (int c = 0; c < 32; ++c) x[c] = lg[c << 7];
    }

    // ---- A3: exp(ll) -> Eb[r*580 + row*36 + cin] ----
    {
        const int cin = l >> 1;
        const int r0  = (l & 1) << 2;
        #pragma unroll
        for (int j = 0; j < 4; ++j) {
            const int row = j * 4 + w;
            float* eb = Eb + row * 36 + cin;
            eb[(r0 + 0) * 580] = __builtin_amdgcn_exp2f(v[j].x * LOG2E);
            eb[(r0 + 1) * 580] = __builtin_amdgcn_exp2f(v[j].y * LOG2E);
            eb[(r0 + 2) * 580] = __builtin_amdgcn_exp2f(v[j].z * LOG2E);
            eb[(r0 + 3) * 580] = __builtin_amdgcn_exp2f(v[j].w * LOG2E);
        }
    }

    // ---- A4: softmax over cin -> Wb slice [(r*2+coH)*268 + coL + cin*8] ----
    if (t < 128) {
        const int r_  = t & 7;
        const int coH = t >> 6;              // (t>>3)>>3, t<128 -> 0..1
        const int coL = (t >> 3) & 7;
        float m = x[0];
        #pragma unroll
        for (int c = 1; c < 32; ++c) m = fmaxf(m, x[c]);
        float s = 0.f;
        #pragma unroll
        for (int c = 0; c < 32; ++c) { x[c] = __builtin_amdgcn_exp2f((x[c] - m) * LOG2E); s += x[c]; }
        const float inv = 1.0f / s;
        float* wrow = Wb + ((r_ << 1) + coH) * 268 + coL;
        #pragma unroll
        for (int c = 0; c < 32; ++c) wrow[c * 8] = x[c] * inv;
    }
    __syncthreads();

    // ---- C: acc[cout8] = sum_cin E[b][cin] * W[cin][cout] ----
    const int r  = (w << 1) + (l >> 5);
    const int ch = (l >> 4) & 1;
    const int b  = l & 15;

    float4 e4[8];
    const float* Ew = Eb + r * 580 + b * 36;
    #pragma unroll
    for (int q = 0; q < 8; ++q) e4[q] = *(const float4*)&Ew[q * 4];

    const float* Ww = Wb + ((r << 1) + ch) * 268;   // uniform per 16-lane group
    float acc[8] = {0.f, 0.f, 0.f, 0.f, 0.f, 0.f, 0.f, 0.f};
    #pragma unroll
    for (int cc = 0; cc < 8; ++cc) {
        #pragma unroll
        for (int i = 0; i < 4; ++i) {
            const float  ev = (i == 0) ? e4[cc].x : (i == 1) ? e4[cc].y : (i == 2) ? e4[cc].z : e4[cc].w;
            const float4 wa = *(const float4*)&Ww[(cc * 4 + i) * 8];
            const float4 wc = *(const float4*)&Ww[(cc * 4 + i) * 8 + 4];
            acc[0] = fmaf(ev, wa.x, acc[0]);
            acc[1] = fmaf(ev, wa.y, acc[1]);
            acc[2] = fmaf(ev, wa.z, acc[2]);
            acc[3] = fmaf(ev, wa.w, acc[3]);
            acc[4] = fmaf(ev, wc.x, acc[4]);
            acc[5] = fmaf(ev, wc.y, acc[5]);
            acc[6] = fmaf(ev, wc.z, acc[6]);
            acc[7] = fmaf(ev, wc.w, acc[7]);
        }
    }
    __syncthreads();                         // all Eb reads done before T2 reuse

    // ---- D: log -> T2[b][cr],  cr = (ch*8+k)*8 + r ----
    #pragma unroll
    for (int k = 0; k < 8; ++k)
        T2[b * 132 + (((ch << 3) + k) << 3) + r] = LN2 * __builtin_amdgcn_logf(acc[k]);
    __syncthreads();

    // ---- E: coalesced writeback of [16 b][128 cr] tile ----
    #pragma unroll
    for (int i = 0; i < 2; ++i) {
        const int q  = i * 256 + t;
        const int bi = q >> 5, c0 = (q & 31) << 2;
        *(float4*)(out + (size_t)(b0 + bi) * 8192 + (f << 7) + c0) =
            *(const float4*)&T2[bi * 132 + c0];
    }
}

extern "C" void kernel_launch(void* const* d_in, const int* in_sizes, int n_in,
                              void* d_out, int out_size, void* d_ws, size_t ws_size,
                              hipStream_t stream) {
    const float* ll     = (const float*)d_in[0];   // (256,64,32,8) f32
    const float* logits = (const float*)d_in[1];   // (64,32,16,8) f32
    float* out = (float*)d_out;                    // (256,64,16,8) f32

    fused_lse<<<dim3(1024), dim3(256), 0, stream>>>(ll, logits, out);
}